// Round 1
// baseline (53.191 us; speedup 1.0000x reference)
//
#include <hip/hip_runtime.h>

// LinearDecayMixup: out[row, :] = one_hot(label) if (rand < ratio && label >= 0)
//                                 else pred[row, :]
// B=64, N=1024, C=768 -> 65536 rows of 768 f32.
// One wave (64 lanes) per row, 3x float4 per lane (64*3*4 = 768).
// Mask is wave-uniform -> no divergence; masked rows skip the pred read.

#define C_CLS 768
#define F4_PER_ROW (C_CLS / 4)   // 192 float4 per row
#define F4_PER_LANE 3            // 64 lanes * 3 f4 = 192

__global__ __launch_bounds__(256) void LinearDecayMixup_kernel(
    const float* __restrict__ pred,       // [rows, 768] f32
    const int*   __restrict__ labels,     // [rows] i32
    const float* __restrict__ rand_nums,  // [rows] f32
    const int*   __restrict__ cur_step_p, // [1]
    const int*   __restrict__ tot_step_p, // [1]
    float*       __restrict__ out,        // [rows, 768] f32
    int n_rows)
{
    // ---- schedule ratio (Python-float semantics, computed in double) ----
    const double cs = (double)cur_step_p[0];
    const double ts = (double)tot_step_p[0];
    double ratio;
    if (cs < ts * 0.2) {
        ratio = 1.0;
    } else if (cs < ts * 0.6) {
        ratio = (ts * 0.6 - cs) / (0.4 * ts);
    } else {
        ratio = 0.0;
    }

    const int lane       = threadIdx.x & 63;
    const int wavesPerBk = blockDim.x >> 6;
    const int totalWaves = gridDim.x * wavesPerBk;
    int wave = blockIdx.x * wavesPerBk + (threadIdx.x >> 6);

    for (int row = wave; row < n_rows; row += totalWaves) {
        const int   label = labels[row];
        const float rn    = rand_nums[row];
        const bool  mask  = ((double)rn < ratio) && (label >= 0);

        const float4* __restrict__ src = (const float4*)pred + (size_t)row * F4_PER_ROW;
        float4*       __restrict__ dst = (float4*)out        + (size_t)row * F4_PER_ROW;

        if (mask) {
            // one-hot row: no pred read needed
            const int lc = min(max(label, 0), C_CLS - 1);
            #pragma unroll
            for (int i = 0; i < F4_PER_LANE; ++i) {
                const int f4   = lane + i * 64;       // coalesced across lanes
                const int base = f4 * 4;
                float4 v;
                v.x = (base + 0 == lc) ? 1.0f : 0.0f;
                v.y = (base + 1 == lc) ? 1.0f : 0.0f;
                v.z = (base + 2 == lc) ? 1.0f : 0.0f;
                v.w = (base + 3 == lc) ? 1.0f : 0.0f;
                dst[f4] = v;
            }
        } else {
            #pragma unroll
            for (int i = 0; i < F4_PER_LANE; ++i) {
                const int f4 = lane + i * 64;         // coalesced across lanes
                dst[f4] = src[f4];
            }
        }
    }
}

extern "C" void kernel_launch(void* const* d_in, const int* in_sizes, int n_in,
                              void* d_out, int out_size, void* d_ws, size_t ws_size,
                              hipStream_t stream) {
    const float* pred      = (const float*)d_in[0];
    const int*   labels    = (const int*)d_in[1];
    const float* rand_nums = (const float*)d_in[2];
    const int*   cur_step  = (const int*)d_in[3];
    const int*   tot_step  = (const int*)d_in[4];
    float*       out       = (float*)d_out;

    const int n_rows = in_sizes[1];  // B*N = 65536

    const int block = 256;                 // 4 waves/block
    const int wavesPerBlock = block / 64;
    int grid = (n_rows + wavesPerBlock - 1) / wavesPerBlock;
    if (grid > 2048) grid = 2048;          // grid-stride the rest

    LinearDecayMixup_kernel<<<grid, block, 0, stream>>>(
        pred, labels, rand_nums, cur_step, tot_step, out, n_rows);
}